// Round 5
// baseline (676.672 us; speedup 1.0000x reference)
//
#include <hip/hip_runtime.h>
#include <hip/hip_bf16.h>

#define N_NODES     50000
#define N_EDGES     1600000
#define N_TOT_EDGES (N_EDGES + N_NODES)
#define NUM_GRAPHS  512
#define F_IN        64
#define F1          128
#define C2          32
#define NEG_SLOPE   0.2f
#define CHUNK       512
#define PAD         16      // counters padded to one per 64B line

typedef __hip_bfloat16 bf16;
typedef unsigned int uint32;
typedef unsigned short ushort;

static __device__ __forceinline__ float bf2f(bf16 v) { return __bfloat162float(v); }
static __device__ __forceinline__ ushort f2bf_bits(float f) {
    __hip_bfloat16 h = __float2bfloat16(f);
    union { __hip_bfloat16 h; ushort u; } c; c.h = h; return c.u;
}
static __device__ __forceinline__ float bflo(uint32 u) { return __uint_as_float(u << 16); }
static __device__ __forceinline__ float bfhi(uint32 u) { return __uint_as_float(u & 0xFFFF0000u); }

static __device__ __forceinline__ float fload(const void* p, int i, bool f32) {
    return f32 ? ((const float*)p)[i] : bf2f(((const bf16*)p)[i]);
}
static __device__ __forceinline__ int iload(const void* p, int i, bool i64) {
    return i64 ? (int)((const long long*)p)[i] : ((const int*)p)[i];
}
static __device__ __forceinline__ float lrelu(float l) { return l > 0.f ? l : NEG_SLOPE * l; }

// ---------------- dtype sniffing ----------------
__global__ void sniff_kernel(const ushort* __restrict__ xb,
                             const int* __restrict__ ei, int* __restrict__ flags) {
    int t = threadIdx.x;
    int badf = 0;
    for (int i = t; i < 8192; i += 256) {
        int e = (xb[i] >> 7) & 0xFF;
        if (e >= 0xC0) badf = 1;   // impossible exponent for N(0,1) bf16 -> it's f32 data
    }
    if (badf) atomicOr(&flags[0], 1);
    if (ei[2 * t + 1] != 0) atomicOr(&flags[1], 1);  // int64 high words all zero
}

// ---------------- CSR build (padded counters: 1 per 64B line) ----------------
__global__ void hist_kernel(const void* __restrict__ ei, const int* __restrict__ flags,
                            int* __restrict__ cntP) {
    bool i64 = (flags[1] == 0);
    int e = blockIdx.x * blockDim.x + threadIdx.x;
    if (e >= N_TOT_EDGES) return;
    int d = (e < N_EDGES) ? iload(ei, N_EDGES + e, i64) : (e - N_EDGES);
    atomicAdd(&cntP[d * PAD], 1);
}

// single-block two-level exclusive scan over padded cnt -> rowptr (compact), cursor (padded)
__global__ void scan_kernel(const int* __restrict__ cntP, int* __restrict__ rowptr,
                            int* __restrict__ curP) {
    __shared__ int lds[1024];
    int t = threadIdx.x;
    const int C = (N_NODES + 1023) >> 10;
    int start = t * C;
    int end = start + C; if (end > N_NODES) end = N_NODES;
    int sum = 0;
    for (int i = start; i < end; ++i) sum += cntP[i * PAD];
    lds[t] = sum;
    __syncthreads();
    for (int off = 1; off < 1024; off <<= 1) {
        int u = (t >= off) ? lds[t - off] : 0;
        __syncthreads();
        lds[t] += u;
        __syncthreads();
    }
    int run = lds[t] - sum;
    for (int i = start; i < end; ++i) {
        int cv = cntP[i * PAD];
        rowptr[i] = run;
        curP[i * PAD] = run;
        run += cv;
    }
    if (t == 0) rowptr[N_NODES] = N_TOT_EDGES;
}

__global__ void scatter_kernel(const void* __restrict__ ei, const int* __restrict__ flags,
                               int* __restrict__ curP, int* __restrict__ col) {
    bool i64 = (flags[1] == 0);
    int e = blockIdx.x * blockDim.x + threadIdx.x;
    if (e >= N_TOT_EDGES) return;
    int s, d;
    if (e < N_EDGES) { s = iload(ei, e, i64); d = iload(ei, N_EDGES + e, i64); }
    else             { s = d = e - N_EDGES; }
    int p = atomicAdd(&curP[d * PAD], 1);
    col[p] = s;
}

// ---------------- Layer 1 GEMM: 4 nodes/block ----------------
__global__ __launch_bounds__(128) void gemm1_kernel(
    const void* __restrict__ x, const void* __restrict__ W1,
    const void* __restrict__ awS, const void* __restrict__ awD,
    const int* __restrict__ flags,
    bf16* __restrict__ h1, float* __restrict__ as1, float* __restrict__ ad1) {
    bool f32 = (flags[0] != 0);
    __shared__ float xs[4][F_IN];
    int n0 = blockIdx.x * 4, tid = threadIdx.x;
    for (int i = tid; i < 4 * F_IN; i += 128)
        xs[i >> 6][i & 63] = fload(x, (n0 + (i >> 6)) * F_IN + (i & 63), f32);
    __syncthreads();
    float acc0 = 0.f, acc1 = 0.f, acc2 = 0.f, acc3 = 0.f;
    if (f32) {
        const float* w = (const float*)W1;
#pragma unroll
        for (int k = 0; k < F_IN; ++k) {
            float wv = w[k * F1 + tid];
            acc0 += xs[0][k] * wv; acc1 += xs[1][k] * wv;
            acc2 += xs[2][k] * wv; acc3 += xs[3][k] * wv;
        }
    } else {
        const bf16* w = (const bf16*)W1;
#pragma unroll
        for (int k = 0; k < F_IN; ++k) {
            float wv = bf2f(w[k * F1 + tid]);
            acc0 += xs[0][k] * wv; acc1 += xs[1][k] * wv;
            acc2 += xs[2][k] * wv; acc3 += xs[3][k] * wv;
        }
    }
    float aws = fload(awS, tid, f32), awd = fload(awD, tid, f32);
    float accs[4] = {acc0, acc1, acc2, acc3};
#pragma unroll
    for (int j = 0; j < 4; ++j) {
        int n = n0 + j;
        h1[n * F1 + tid] = __float2bfloat16(accs[j]);
        float ps = accs[j] * aws, pd = accs[j] * awd;
#pragma unroll
        for (int off = 16; off > 0; off >>= 1) {
            ps += __shfl_down(ps, off, 32);
            pd += __shfl_down(pd, off, 32);
        }
        if ((tid & 31) == 0) {
            as1[n * 4 + (tid >> 5)] = ps;
            ad1[n * 4 + (tid >> 5)] = pd;
        }
    }
}

// ---------------- Layer 1 aggregation: fused 2-phase, 1 wave/node ----------------
__global__ __launch_bounds__(64) void agg1_kernel(
    const bf16* __restrict__ h1, const float* __restrict__ as1, const float* __restrict__ ad1,
    const int* __restrict__ rowptr, const int* __restrict__ col,
    const void* __restrict__ b1, const int* __restrict__ flags, bf16* __restrict__ y1) {
    __shared__ float4 wbuf[CHUNK];
    __shared__ int    scol[CHUNK];
    bool f32 = (flags[0] != 0);
    int n = blockIdx.x, lane = threadIdx.x;
    int r0 = rowptr[n], r1 = rowptr[n + 1];
    const float4* as1v = (const float4*)as1;
    float4 ad = ((const float4*)ad1)[n];
    const uint32* h1u = (const uint32*)h1;
    int h = lane >> 4;
    float acc0 = 0.f, acc1 = 0.f, den = 0.f;

    for (int base = r0; base < r1; base += CHUNK) {
        int ce = base + CHUNK; if (ce > r1) ce = r1;
        int cnt = ce - base;
        for (int e = base + lane; e < ce; e += 64) {
            int s = col[e];
            float4 a = as1v[s];
            float4 w;
            w.x = __expf(lrelu(a.x + ad.x));
            w.y = __expf(lrelu(a.y + ad.y));
            w.z = __expf(lrelu(a.z + ad.z));
            w.w = __expf(lrelu(a.w + ad.w));
            wbuf[e - base] = w;
            scol[e - base] = s;
        }
        __syncthreads();
        const float* wf = (const float*)wbuf;
        for (int i = 0; i < cnt; ++i) {
            int s = scol[i];
            float w = wf[i * 4 + h];
            uint32 u = h1u[s * 64 + lane];   // full 256B row per wave
            acc0 += w * bflo(u);
            acc1 += w * bfhi(u);
            den  += w;
        }
        __syncthreads();
    }
    float rd = 1.f / den;
    int c0 = lane * 2;
    float o0 = acc0 * rd + fload(b1, c0, f32);
    float o1 = acc1 * rd + fload(b1, c0 + 1, f32);
    o0 = o0 > 0.f ? o0 : (__expf(o0) - 1.f);
    o1 = o1 > 0.f ? o1 : (__expf(o1) - 1.f);
    ushort2 st; st.x = f2bf_bits(o0); st.y = f2bf_bits(o1);
    ((ushort2*)y1)[n * 64 + lane] = st;
}

// ---------------- Layer 2 GEMM ----------------
__global__ __launch_bounds__(128) void gemm2_kernel(
    const bf16* __restrict__ y1, const void* __restrict__ W2,
    const void* __restrict__ aS, const void* __restrict__ aD,
    const int* __restrict__ flags,
    bf16* __restrict__ h2, float* __restrict__ as2, float* __restrict__ ad2) {
    bool f32 = (flags[0] != 0);
    __shared__ float ys[F1];
    __shared__ float part[F1];
    int n = blockIdx.x, tid = threadIdx.x, c = tid & 31, q = tid >> 5;
    ys[tid] = bf2f(y1[n * F1 + tid]);
    __syncthreads();
    float acc = 0.f;
    if (f32) {
        const float* w = (const float*)W2;
#pragma unroll
        for (int k = 0; k < 32; ++k) { int f = q * 32 + k; acc += ys[f] * w[f * C2 + c]; }
    } else {
        const bf16* w = (const bf16*)W2;
#pragma unroll
        for (int k = 0; k < 32; ++k) { int f = q * 32 + k; acc += ys[f] * bf2f(w[f * C2 + c]); }
    }
    part[tid] = acc;
    __syncthreads();
    if (q == 0) {
        float s = part[c] + part[32 + c] + part[64 + c] + part[96 + c];
        h2[n * C2 + c] = __float2bfloat16(s);
        float ps = s * fload(aS, c, f32);
        float pd = s * fload(aD, c, f32);
#pragma unroll
        for (int off = 16; off > 0; off >>= 1) {
            ps += __shfl_down(ps, off, 32);
            pd += __shfl_down(pd, off, 32);
        }
        if (c == 0) { as2[n] = ps; ad2[n] = pd; }
    }
}

// ---------------- Layer 2 aggregation: fused 2-phase, 1 wave/node, 4 edges/iter ----------------
__global__ __launch_bounds__(64) void agg2_kernel(
    const bf16* __restrict__ h2, const float* __restrict__ as2, const float* __restrict__ ad2,
    const int* __restrict__ rowptr, const int* __restrict__ col,
    const void* __restrict__ b2, const int* __restrict__ flags, float* __restrict__ v2) {
    __shared__ float wl[CHUNK];
    __shared__ int   scol[CHUNK];
    bool f32 = (flags[0] != 0);
    int n = blockIdx.x, lane = threadIdx.x;
    int r0 = rowptr[n], r1 = rowptr[n + 1];
    float adn = ad2[n];
    const uint32* h2u = (const uint32*)h2;
    int slot = lane >> 4, cl = lane & 15;
    float acc0 = 0.f, acc1 = 0.f, den = 0.f;

    for (int base = r0; base < r1; base += CHUNK) {
        int ce = base + CHUNK; if (ce > r1) ce = r1;
        int cnt = ce - base;
        for (int e = base + lane; e < ce; e += 64) {
            int s = col[e];
            wl[e - base] = __expf(lrelu(as2[s] + adn));
            scol[e - base] = s;
        }
        __syncthreads();
        for (int i = slot; i < cnt; i += 4) {
            int s = scol[i];
            float w = wl[i];
            uint32 u = h2u[s * 16 + cl];    // 64B row per 16-lane group
            acc0 += w * bflo(u);
            acc1 += w * bfhi(u);
            den  += w;
        }
        __syncthreads();
    }
#pragma unroll
    for (int off = 16; off <= 32; off <<= 1) {
        acc0 += __shfl_xor(acc0, off, 64);
        acc1 += __shfl_xor(acc1, off, 64);
        den  += __shfl_xor(den,  off, 64);
    }
    if (lane < 16) {
        float rd = 1.f / den;
        float2 o;
        o.x = acc0 * rd + fload(b2, 2 * lane, f32);
        o.y = acc1 * rd + fload(b2, 2 * lane + 1, f32);
        ((float2*)v2)[n * 16 + lane] = o;
    }
}

// ---------------- Pool: batch is sorted -> binary search ranges, no atomics ----------------
__global__ __launch_bounds__(64) void pool_kernel(
    const float* __restrict__ v2, const void* __restrict__ batch,
    const int* __restrict__ flags, void* __restrict__ out) {
    bool f32 = (flags[0] != 0);
    bool i64 = (flags[1] == 0);
    int g = blockIdx.x, lane = threadIdx.x;
    int lo = 0, hi = N_NODES;
    while (lo < hi) { int mid = (lo + hi) >> 1; if (iload(batch, mid, i64) < g) lo = mid + 1; else hi = mid; }
    int lo2 = lo, hi2 = N_NODES;
    while (lo2 < hi2) { int mid = (lo2 + hi2) >> 1; if (iload(batch, mid, i64) < g + 1) lo2 = mid + 1; else hi2 = mid; }
    int c = lane & 31, slot = lane >> 5;
    float sum = 0.f;
    for (int nn = lo + slot; nn < lo2; nn += 2) sum += v2[nn * C2 + c];
    sum += __shfl_down(sum, 32, 64);
    if (lane < 32) {
        int cntn = lo2 - lo; if (cntn < 1) cntn = 1;
        float v = sum / (float)cntn;
        if (f32) ((float*)out)[g * C2 + c] = v;
        else     ((bf16*)out)[g * C2 + c] = __float2bfloat16(v);
    }
}

// ---------------- launcher ----------------
extern "C" void kernel_launch(void* const* d_in, const int* in_sizes, int n_in,
                              void* d_out, int out_size, void* d_ws, size_t ws_size,
                              hipStream_t stream) {
    const void* x   = d_in[0];
    const void* ei  = d_in[1];
    const void* bat = d_in[2];
    const void* W1  = d_in[4];
    const void* aS1 = d_in[5];
    const void* aD1 = d_in[6];
    const void* b1  = d_in[7];
    const void* W2  = d_in[8];
    const void* aS2 = d_in[9];
    const void* aD2 = d_in[10];
    const void* b2  = d_in[11];

    char* p = (char*)d_ws;
    auto alloc = [&](size_t bytes) -> char* {
        char* r = p;
        p += (bytes + 255) & ~size_t(255);
        return r;
    };
    // Region A (12.8MB): padded cnt during CSR build -> h1 (bf16) -> h2 (bf16)
    // Region B (12.8MB): padded cursor during CSR build -> y1 (bf16) -> v2 (f32)
    // (CSR build fully completes on-stream before gemm1 writes h1 / agg1 writes y1)
    char* regionA = alloc((size_t)N_NODES * F1 * 2);
    char* regionB = alloc((size_t)N_NODES * F1 * 2);
    int*   cntP = (int*)regionA;   // N_NODES*PAD ints = 3.2M ints = 12.8MB ✓
    bf16*  h1   = (bf16*)regionA;
    bf16*  h2   = (bf16*)regionA;
    int*   curP = (int*)regionB;
    bf16*  y1   = (bf16*)regionB;
    float* v2   = (float*)regionB;
    float* as1    = (float*)alloc((size_t)N_NODES * 4 * 4);
    float* ad1    = (float*)alloc((size_t)N_NODES * 4 * 4);
    float* as2    = (float*)alloc((size_t)N_NODES * 4);
    float* ad2    = (float*)alloc((size_t)N_NODES * 4);
    int*   rowptr = (int*)alloc((size_t)(N_NODES + 1) * 4);
    int*   col    = (int*)alloc((size_t)N_TOT_EDGES * 4);
    int*   flags  = (int*)alloc(64);
    // total ~34.4 MB

    (void)hipMemsetAsync(cntP, 0, (size_t)N_NODES * PAD * 4, stream);
    (void)hipMemsetAsync(flags, 0, 64, stream);

    sniff_kernel<<<1, 256, 0, stream>>>((const ushort*)x, (const int*)ei, flags);

    int eb = (N_TOT_EDGES + 255) / 256;
    hist_kernel<<<eb, 256, 0, stream>>>(ei, flags, cntP);
    scan_kernel<<<1, 1024, 0, stream>>>(cntP, rowptr, curP);
    scatter_kernel<<<eb, 256, 0, stream>>>(ei, flags, curP, col);

    gemm1_kernel<<<N_NODES / 4, 128, 0, stream>>>(x, W1, aS1, aD1, flags, h1, as1, ad1);
    agg1_kernel<<<N_NODES, 64, 0, stream>>>(h1, as1, ad1, rowptr, col, b1, flags, y1);
    gemm2_kernel<<<N_NODES, 128, 0, stream>>>(y1, W2, aS2, aD2, flags, h2, as2, ad2);
    agg2_kernel<<<N_NODES, 64, 0, stream>>>(h2, as2, ad2, rowptr, col, b2, flags, v2);
    pool_kernel<<<NUM_GRAPHS, 64, 0, stream>>>(v2, bat, flags, d_out);
}

// Round 6
// 361.609 us; speedup vs baseline: 1.8713x; 1.8713x over previous
//
#include <hip/hip_runtime.h>
#include <hip/hip_bf16.h>

#define N_NODES     50000
#define N_EDGES     1600000
#define N_TOT_EDGES (N_EDGES + N_NODES)
#define NUM_GRAPHS  512
#define F_IN        64
#define F1          128
#define C2          32
#define NEG_SLOPE   0.2f
#define CHUNK       512

// counting-sort CSR build
#define BSH         6                       // 64 nodes per bucket
#define NB          ((N_NODES + 63) >> 6)   // 782 buckets
#define BIN_T       512                     // threads in K1/K3
#define EPB         16384                   // edges per block in K1/K3
#define NBLK        ((N_TOT_EDGES + EPB - 1) / EPB)   // 101
#define CAP         6144                    // LDS col staging capacity per bucket

typedef __hip_bfloat16 bf16;
typedef unsigned int uint32;
typedef unsigned short ushort;

static __device__ __forceinline__ float bf2f(bf16 v) { return __bfloat162float(v); }
static __device__ __forceinline__ ushort f2bf_bits(float f) {
    __hip_bfloat16 h = __float2bfloat16(f);
    union { __hip_bfloat16 h; ushort u; } c; c.h = h; return c.u;
}
static __device__ __forceinline__ float bflo(uint32 u) { return __uint_as_float(u << 16); }
static __device__ __forceinline__ float bfhi(uint32 u) { return __uint_as_float(u & 0xFFFF0000u); }

static __device__ __forceinline__ float fload(const void* p, int i, bool f32) {
    return f32 ? ((const float*)p)[i] : bf2f(((const bf16*)p)[i]);
}
static __device__ __forceinline__ int iload(const void* p, int i, bool i64) {
    return i64 ? (int)((const long long*)p)[i] : ((const int*)p)[i];
}
static __device__ __forceinline__ float lrelu(float l) { return l > 0.f ? l : NEG_SLOPE * l; }

// ---------------- dtype sniffing ----------------
__global__ void sniff_kernel(const ushort* __restrict__ xb,
                             const int* __restrict__ ei, int* __restrict__ flags) {
    int t = threadIdx.x;
    int badf = 0;
    for (int i = t; i < 8192; i += 256) {
        int e = (xb[i] >> 7) & 0xFF;
        if (e >= 0xC0) badf = 1;   // impossible exponent for N(0,1) bf16 -> it's f32 data
    }
    if (badf) atomicOr(&flags[0], 1);
    if (ei[2 * t + 1] != 0) atomicOr(&flags[1], 1);  // int64 high words all zero
}

// ---------------- CSR build: 2-level counting sort ----------------
// K1: per-block LDS bucket histogram -> merge to global (79k atomics total)
__global__ __launch_bounds__(BIN_T) void bucket_hist_kernel(
    const void* __restrict__ ei, const int* __restrict__ flags, int* __restrict__ gcnt) {
    __shared__ int lcnt[NB];
    bool i64 = (flags[1] == 0);
    for (int b = threadIdx.x; b < NB; b += BIN_T) lcnt[b] = 0;
    __syncthreads();
    int e0 = blockIdx.x * EPB;
#pragma unroll 4
    for (int it = 0; it < EPB / BIN_T; ++it) {
        int e = e0 + it * BIN_T + threadIdx.x;
        if (e < N_TOT_EDGES) {
            int d = (e < N_EDGES) ? iload(ei, N_EDGES + e, i64) : (e - N_EDGES);
            atomicAdd(&lcnt[d >> BSH], 1);
        }
    }
    __syncthreads();
    for (int b = threadIdx.x; b < NB; b += BIN_T)
        if (lcnt[b]) atomicAdd(&gcnt[b], lcnt[b]);
}

// K2: one-block scan of NB bucket counts -> bucketBase[NB+1], cursor
__global__ __launch_bounds__(1024) void bucket_scan_kernel(
    const int* __restrict__ gcnt, int* __restrict__ bucketBase, int* __restrict__ cursor) {
    __shared__ int lds[1024];
    int t = threadIdx.x;
    int v = (t < NB) ? gcnt[t] : 0;
    lds[t] = v;
    __syncthreads();
    for (int off = 1; off < 1024; off <<= 1) {
        int u = (t >= off) ? lds[t - off] : 0;
        __syncthreads();
        lds[t] += u;
        __syncthreads();
    }
    if (t < NB) {
        int base = lds[t] - v;   // exclusive
        bucketBase[t] = base;
        cursor[t] = base;
    }
    if (t == NB - 1) bucketBase[NB] = lds[t];
}

// K3: binning — per-block LDS hist, reserve runs, write packed (dlocal<<16|src) in runs
__global__ __launch_bounds__(BIN_T) void bin_kernel(
    const void* __restrict__ ei, const int* __restrict__ flags,
    int* __restrict__ cursor, uint32* __restrict__ packed) {
    __shared__ int lcnt[NB];
    __shared__ int loff[NB];
    __shared__ int runB[NB];
    bool i64 = (flags[1] == 0);
    for (int b = threadIdx.x; b < NB; b += BIN_T) { lcnt[b] = 0; loff[b] = 0; }
    __syncthreads();
    int e0 = blockIdx.x * EPB;
#pragma unroll 4
    for (int it = 0; it < EPB / BIN_T; ++it) {
        int e = e0 + it * BIN_T + threadIdx.x;
        if (e < N_TOT_EDGES) {
            int d = (e < N_EDGES) ? iload(ei, N_EDGES + e, i64) : (e - N_EDGES);
            atomicAdd(&lcnt[d >> BSH], 1);
        }
    }
    __syncthreads();
    for (int b = threadIdx.x; b < NB; b += BIN_T)
        runB[b] = lcnt[b] ? atomicAdd(&cursor[b], lcnt[b]) : 0;
    __syncthreads();
#pragma unroll 4
    for (int it = 0; it < EPB / BIN_T; ++it) {
        int e = e0 + it * BIN_T + threadIdx.x;
        if (e < N_TOT_EDGES) {
            int s, d;
            if (e < N_EDGES) { s = iload(ei, e, i64); d = iload(ei, N_EDGES + e, i64); }
            else             { s = d = e - N_EDGES; }
            int b = d >> BSH;
            int r = atomicAdd(&loff[b], 1);
            // run positions are block-private -> write-combined within one CU
            packed[runB[b] + r] = ((uint32)(d & 63) << 16) | (uint32)s;
        }
    }
}

// K4: per-bucket CSR finalize — node hist, scan, LDS-staged col, coalesced writes
__global__ __launch_bounds__(256) void build_kernel(
    const uint32* __restrict__ packed, const int* __restrict__ bucketBase,
    int* __restrict__ rowptr, int* __restrict__ col) {
    __shared__ int ncnt[64];
    __shared__ int nbase[64];
    __shared__ int ncur[64];
    __shared__ int colL[CAP];
    int b = blockIdx.x, tid = threadIdx.x;
    int base = bucketBase[b];
    int cnt = bucketBase[b + 1] - base;
    int n0 = b << BSH;
    if (tid < 64) ncnt[tid] = 0;
    __syncthreads();
    for (int i = tid; i < cnt; i += 256)
        atomicAdd(&ncnt[packed[base + i] >> 16], 1);
    __syncthreads();
    if (tid == 0) {
        int run = 0;
        for (int j = 0; j < 64; ++j) { nbase[j] = run; ncur[j] = run; run += ncnt[j]; }
    }
    __syncthreads();
    if (tid < 64 && n0 + tid < N_NODES) rowptr[n0 + tid] = base + nbase[tid];
    if (b == 0 && tid == 64 + 32) rowptr[N_NODES] = N_TOT_EDGES;
    bool staged = (cnt <= CAP);
    for (int i = tid; i < cnt; i += 256) {
        uint32 u = packed[base + i];
        int r = atomicAdd(&ncur[u >> 16], 1);
        if (staged) colL[r] = (int)(u & 0xFFFFu);
        else        col[base + r] = (int)(u & 0xFFFFu);   // fallback (never expected)
    }
    __syncthreads();
    if (staged)
        for (int i = tid; i < cnt; i += 256) col[base + i] = colL[i];
}

// ---------------- Layer 1 GEMM: 4 nodes/block ----------------
__global__ __launch_bounds__(128) void gemm1_kernel(
    const void* __restrict__ x, const void* __restrict__ W1,
    const void* __restrict__ awS, const void* __restrict__ awD,
    const int* __restrict__ flags,
    bf16* __restrict__ h1, float* __restrict__ as1, float* __restrict__ ad1) {
    bool f32 = (flags[0] != 0);
    __shared__ float xs[4][F_IN];
    int n0 = blockIdx.x * 4, tid = threadIdx.x;
    for (int i = tid; i < 4 * F_IN; i += 128)
        xs[i >> 6][i & 63] = fload(x, (n0 + (i >> 6)) * F_IN + (i & 63), f32);
    __syncthreads();
    float acc0 = 0.f, acc1 = 0.f, acc2 = 0.f, acc3 = 0.f;
    if (f32) {
        const float* w = (const float*)W1;
#pragma unroll
        for (int k = 0; k < F_IN; ++k) {
            float wv = w[k * F1 + tid];
            acc0 += xs[0][k] * wv; acc1 += xs[1][k] * wv;
            acc2 += xs[2][k] * wv; acc3 += xs[3][k] * wv;
        }
    } else {
        const bf16* w = (const bf16*)W1;
#pragma unroll
        for (int k = 0; k < F_IN; ++k) {
            float wv = bf2f(w[k * F1 + tid]);
            acc0 += xs[0][k] * wv; acc1 += xs[1][k] * wv;
            acc2 += xs[2][k] * wv; acc3 += xs[3][k] * wv;
        }
    }
    float aws = fload(awS, tid, f32), awd = fload(awD, tid, f32);
    float accs[4] = {acc0, acc1, acc2, acc3};
#pragma unroll
    for (int j = 0; j < 4; ++j) {
        int n = n0 + j;
        h1[n * F1 + tid] = __float2bfloat16(accs[j]);
        float ps = accs[j] * aws, pd = accs[j] * awd;
#pragma unroll
        for (int off = 16; off > 0; off >>= 1) {
            ps += __shfl_down(ps, off, 32);
            pd += __shfl_down(pd, off, 32);
        }
        if ((tid & 31) == 0) {
            as1[n * 4 + (tid >> 5)] = ps;
            ad1[n * 4 + (tid >> 5)] = pd;
        }
    }
}

// ---------------- Layer 1 aggregation: fused 2-phase, 1 wave/node ----------------
__global__ __launch_bounds__(64) void agg1_kernel(
    const bf16* __restrict__ h1, const float* __restrict__ as1, const float* __restrict__ ad1,
    const int* __restrict__ rowptr, const int* __restrict__ col,
    const void* __restrict__ b1, const int* __restrict__ flags, bf16* __restrict__ y1) {
    __shared__ float4 wbuf[CHUNK];
    __shared__ int    scol[CHUNK];
    bool f32 = (flags[0] != 0);
    int n = blockIdx.x, lane = threadIdx.x;
    int r0 = rowptr[n], r1 = rowptr[n + 1];
    const float4* as1v = (const float4*)as1;
    float4 ad = ((const float4*)ad1)[n];
    const uint32* h1u = (const uint32*)h1;
    int h = lane >> 4;
    float acc0 = 0.f, acc1 = 0.f, den = 0.f;

    for (int base = r0; base < r1; base += CHUNK) {
        int ce = base + CHUNK; if (ce > r1) ce = r1;
        int cnt = ce - base;
        for (int e = base + lane; e < ce; e += 64) {
            int s = col[e];
            float4 a = as1v[s];
            float4 w;
            w.x = __expf(lrelu(a.x + ad.x));
            w.y = __expf(lrelu(a.y + ad.y));
            w.z = __expf(lrelu(a.z + ad.z));
            w.w = __expf(lrelu(a.w + ad.w));
            wbuf[e - base] = w;
            scol[e - base] = s;
        }
        __syncthreads();
        const float* wf = (const float*)wbuf;
        for (int i = 0; i < cnt; ++i) {
            int s = scol[i];
            float w = wf[i * 4 + h];
            uint32 u = h1u[s * 64 + lane];   // full 256B row per wave
            acc0 += w * bflo(u);
            acc1 += w * bfhi(u);
            den  += w;
        }
        __syncthreads();
    }
    float rd = 1.f / den;
    int c0 = lane * 2;
    float o0 = acc0 * rd + fload(b1, c0, f32);
    float o1 = acc1 * rd + fload(b1, c0 + 1, f32);
    o0 = o0 > 0.f ? o0 : (__expf(o0) - 1.f);
    o1 = o1 > 0.f ? o1 : (__expf(o1) - 1.f);
    ushort2 st; st.x = f2bf_bits(o0); st.y = f2bf_bits(o1);
    ((ushort2*)y1)[n * 64 + lane] = st;
}

// ---------------- Layer 2 GEMM ----------------
__global__ __launch_bounds__(128) void gemm2_kernel(
    const bf16* __restrict__ y1, const void* __restrict__ W2,
    const void* __restrict__ aS, const void* __restrict__ aD,
    const int* __restrict__ flags,
    bf16* __restrict__ h2, float* __restrict__ as2, float* __restrict__ ad2) {
    bool f32 = (flags[0] != 0);
    __shared__ float ys[F1];
    __shared__ float part[F1];
    int n = blockIdx.x, tid = threadIdx.x, c = tid & 31, q = tid >> 5;
    ys[tid] = bf2f(y1[n * F1 + tid]);
    __syncthreads();
    float acc = 0.f;
    if (f32) {
        const float* w = (const float*)W2;
#pragma unroll
        for (int k = 0; k < 32; ++k) { int f = q * 32 + k; acc += ys[f] * w[f * C2 + c]; }
    } else {
        const bf16* w = (const bf16*)W2;
#pragma unroll
        for (int k = 0; k < 32; ++k) { int f = q * 32 + k; acc += ys[f] * bf2f(w[f * C2 + c]); }
    }
    part[tid] = acc;
    __syncthreads();
    if (q == 0) {
        float s = part[c] + part[32 + c] + part[64 + c] + part[96 + c];
        h2[n * C2 + c] = __float2bfloat16(s);
        float ps = s * fload(aS, c, f32);
        float pd = s * fload(aD, c, f32);
#pragma unroll
        for (int off = 16; off > 0; off >>= 1) {
            ps += __shfl_down(ps, off, 32);
            pd += __shfl_down(pd, off, 32);
        }
        if (c == 0) { as2[n] = ps; ad2[n] = pd; }
    }
}

// ---------------- Layer 2 aggregation ----------------
__global__ __launch_bounds__(64) void agg2_kernel(
    const bf16* __restrict__ h2, const float* __restrict__ as2, const float* __restrict__ ad2,
    const int* __restrict__ rowptr, const int* __restrict__ col,
    const void* __restrict__ b2, const int* __restrict__ flags, float* __restrict__ v2) {
    __shared__ float wl[CHUNK];
    __shared__ int   scol[CHUNK];
    bool f32 = (flags[0] != 0);
    int n = blockIdx.x, lane = threadIdx.x;
    int r0 = rowptr[n], r1 = rowptr[n + 1];
    float adn = ad2[n];
    const uint32* h2u = (const uint32*)h2;
    int slot = lane >> 4, cl = lane & 15;
    float acc0 = 0.f, acc1 = 0.f, den = 0.f;

    for (int base = r0; base < r1; base += CHUNK) {
        int ce = base + CHUNK; if (ce > r1) ce = r1;
        int cnt = ce - base;
        for (int e = base + lane; e < ce; e += 64) {
            int s = col[e];
            wl[e - base] = __expf(lrelu(as2[s] + adn));
            scol[e - base] = s;
        }
        __syncthreads();
        for (int i = slot; i < cnt; i += 4) {
            int s = scol[i];
            float w = wl[i];
            uint32 u = h2u[s * 16 + cl];
            acc0 += w * bflo(u);
            acc1 += w * bfhi(u);
            den  += w;
        }
        __syncthreads();
    }
#pragma unroll
    for (int off = 16; off <= 32; off <<= 1) {
        acc0 += __shfl_xor(acc0, off, 64);
        acc1 += __shfl_xor(acc1, off, 64);
        den  += __shfl_xor(den,  off, 64);
    }
    if (lane < 16) {
        float rd = 1.f / den;
        float2 o;
        o.x = acc0 * rd + fload(b2, 2 * lane, f32);
        o.y = acc1 * rd + fload(b2, 2 * lane + 1, f32);
        ((float2*)v2)[n * 16 + lane] = o;
    }
}

// ---------------- Pool ----------------
__global__ __launch_bounds__(64) void pool_kernel(
    const float* __restrict__ v2, const void* __restrict__ batch,
    const int* __restrict__ flags, void* __restrict__ out) {
    bool f32 = (flags[0] != 0);
    bool i64 = (flags[1] == 0);
    int g = blockIdx.x, lane = threadIdx.x;
    int lo = 0, hi = N_NODES;
    while (lo < hi) { int mid = (lo + hi) >> 1; if (iload(batch, mid, i64) < g) lo = mid + 1; else hi = mid; }
    int lo2 = lo, hi2 = N_NODES;
    while (lo2 < hi2) { int mid = (lo2 + hi2) >> 1; if (iload(batch, mid, i64) < g + 1) lo2 = mid + 1; else hi2 = mid; }
    int c = lane & 31, slot = lane >> 5;
    float sum = 0.f;
    for (int nn = lo + slot; nn < lo2; nn += 2) sum += v2[nn * C2 + c];
    sum += __shfl_down(sum, 32, 64);
    if (lane < 32) {
        int cntn = lo2 - lo; if (cntn < 1) cntn = 1;
        float v = sum / (float)cntn;
        if (f32) ((float*)out)[g * C2 + c] = v;
        else     ((bf16*)out)[g * C2 + c] = __float2bfloat16(v);
    }
}

// ---------------- launcher ----------------
extern "C" void kernel_launch(void* const* d_in, const int* in_sizes, int n_in,
                              void* d_out, int out_size, void* d_ws, size_t ws_size,
                              hipStream_t stream) {
    const void* x   = d_in[0];
    const void* ei  = d_in[1];
    const void* bat = d_in[2];
    const void* W1  = d_in[4];
    const void* aS1 = d_in[5];
    const void* aD1 = d_in[6];
    const void* b1  = d_in[7];
    const void* W2  = d_in[8];
    const void* aS2 = d_in[9];
    const void* aD2 = d_in[10];
    const void* b2  = d_in[11];

    char* p = (char*)d_ws;
    auto alloc = [&](size_t bytes) -> char* {
        char* r = p;
        p += (bytes + 255) & ~size_t(255);
        return r;
    };
    // Region A (12.8MB): packed edge array (6.6MB, CSR build) -> h1 (bf16) -> h2 (bf16)
    // Region B (12.8MB): y1 (bf16) -> v2 (f32)
    char* regionA = alloc((size_t)N_NODES * F1 * 2);
    char* regionB = alloc((size_t)N_NODES * F1 * 2);
    uint32* packed = (uint32*)regionA;
    bf16*  h1   = (bf16*)regionA;
    bf16*  h2   = (bf16*)regionA;
    bf16*  y1   = (bf16*)regionB;
    float* v2   = (float*)regionB;
    float* as1    = (float*)alloc((size_t)N_NODES * 4 * 4);
    float* ad1    = (float*)alloc((size_t)N_NODES * 4 * 4);
    float* as2    = (float*)alloc((size_t)N_NODES * 4);
    float* ad2    = (float*)alloc((size_t)N_NODES * 4);
    int*   rowptr = (int*)alloc((size_t)(N_NODES + 1) * 4);
    int*   col    = (int*)alloc((size_t)N_TOT_EDGES * 4);
    int*   gcnt   = (int*)alloc((size_t)NB * 4);
    int*   bucketBase = (int*)alloc((size_t)(NB + 1) * 4);
    int*   cursor = (int*)alloc((size_t)NB * 4);
    int*   flags  = (int*)alloc(64);
    // total ~34 MB

    (void)hipMemsetAsync(gcnt, 0, (size_t)NB * 4, stream);
    (void)hipMemsetAsync(flags, 0, 64, stream);

    sniff_kernel<<<1, 256, 0, stream>>>((const ushort*)x, (const int*)ei, flags);

    bucket_hist_kernel<<<NBLK, BIN_T, 0, stream>>>(ei, flags, gcnt);
    bucket_scan_kernel<<<1, 1024, 0, stream>>>(gcnt, bucketBase, cursor);
    bin_kernel<<<NBLK, BIN_T, 0, stream>>>(ei, flags, cursor, packed);
    build_kernel<<<NB, 256, 0, stream>>>(packed, bucketBase, rowptr, col);

    gemm1_kernel<<<N_NODES / 4, 128, 0, stream>>>(x, W1, aS1, aD1, flags, h1, as1, ad1);
    agg1_kernel<<<N_NODES, 64, 0, stream>>>(h1, as1, ad1, rowptr, col, b1, flags, y1);
    gemm2_kernel<<<N_NODES, 128, 0, stream>>>(y1, W2, aS2, aD2, flags, h2, as2, ad2);
    agg2_kernel<<<N_NODES, 64, 0, stream>>>(h2, as2, ad2, rowptr, col, b2, flags, v2);
    pool_kernel<<<NUM_GRAPHS, 64, 0, stream>>>(v2, bat, flags, d_out);
}